// Round 1
// baseline (258.919 us; speedup 1.0000x reference)
//
#include <hip/hip_runtime.h>

// ColorHistogramLoss: B=32, C=3, H=W=512, BINS=64.
// loss = mean_{B×(C·BINS)} | hist(input) - hist(target) |, hist normalized by N=H*W.
//
// v2: ballot bit-slice histogram. BINS == wavefront size (64), so lane L owns
// bin L in a register. Per element round: 7 ballots (6 bin bits + validity),
// per-lane precomputed XOR masks, one popcll. Zero LDS atomics in the hot loop
// (previous version serialized ~100M ds_add RMWs -> 214 us vs ~32 us HBM floor).

#define BINS 64
#define PLANES 96          // B*C
#define PLANE_F4 65536     // 512*512/4
#define SEGS 32            // segments per plane
#define SEG_F4 2048        // PLANE_F4/SEGS
#define TPB 256
#define F4T 8              // SEG_F4/TPB float4 per thread per tensor

struct Inv {
    unsigned long long b0, b1, b2, b3, b4, b5;
};

// Count, across the wave, how many of this round's 64 elements land in bin==lane.
// Binning identical to verified v1: bin = floor((v+1)*31.5); v<-1 invalid; v>=1 -> 63.
__device__ __forceinline__ int count_elem(float v, const Inv& iv) {
    int bin = (int)floorf((v + 1.0f) * 31.5f);
    int cb  = bin > 63 ? 63 : bin;
    unsigned long long m = __ballot(bin >= 0);          // validity mask
    m &= __ballot(cb & 1)  ^ iv.b0;
    m &= __ballot(cb & 2)  ^ iv.b1;
    m &= __ballot(cb & 4)  ^ iv.b2;
    m &= __ballot(cb & 8)  ^ iv.b3;
    m &= __ballot(cb & 16) ^ iv.b4;
    m &= __ballot(cb & 32) ^ iv.b5;
    return __popcll(m);                                  // lanes whose bin == my lane
}

__device__ __forceinline__ int count4(float4 a, const Inv& iv) {
    return count_elem(a.x, iv) + count_elem(a.y, iv)
         + count_elem(a.z, iv) + count_elem(a.w, iv);
}

__global__ __launch_bounds__(TPB) void hist_diff_kernel(
        const float4* __restrict__ in4, const float4* __restrict__ tg4,
        int* __restrict__ gdiff) {
    const int tid  = threadIdx.x;
    const int lane = tid & 63;

    // inv_b: bit b of my lane set ? 0 : ~0  (per-lane constants, ~12 VGPRs)
    Inv iv;
    iv.b0 = (lane & 1)  ? 0ULL : ~0ULL;
    iv.b1 = (lane & 2)  ? 0ULL : ~0ULL;
    iv.b2 = (lane & 4)  ? 0ULL : ~0ULL;
    iv.b3 = (lane & 8)  ? 0ULL : ~0ULL;
    iv.b4 = (lane & 16) ? 0ULL : ~0ULL;
    iv.b5 = (lane & 32) ? 0ULL : ~0ULL;

    const int plane = blockIdx.x >> 5;           // /SEGS
    const int seg   = blockIdx.x & (SEGS - 1);
    const long base = (long)plane * PLANE_F4 + (long)seg * SEG_F4 + tid;

    int acc = 0;   // signed count of (bin == lane) for this wave: input minus target

    // depth-1 prefetch keeps live VGPRs low (8 waves/SIMD) while hiding load latency
    float4 cur = in4[base];
#pragma unroll
    for (int k = 0; k < F4T; ++k) {
        float4 nxt = (k + 1 < F4T) ? in4[base + (k + 1) * TPB] : tg4[base];
        acc += count4(cur, iv);
        cur = nxt;
    }
#pragma unroll
    for (int k = 0; k < F4T; ++k) {
        float4 nxt = (k + 1 < F4T) ? tg4[base + (k + 1) * TPB]
                                   : make_float4(-2.f, -2.f, -2.f, -2.f);
        acc -= count4(cur, iv);
        cur = nxt;
    }

    // merge 4 waves -> block histogram (4 ds_add instrs total, 2-way bank alias: free)
    __shared__ int lh[BINS];
    if (tid < BINS) lh[tid] = 0;
    __syncthreads();
    atomicAdd(&lh[lane], acc);
    __syncthreads();
    if (tid < BINS) {
        int v = lh[tid];
        if (v != 0) atomicAdd(&gdiff[plane * BINS + tid], v);
    }
}

__global__ __launch_bounds__(TPB) void reduce_abs_kernel(
        const int* __restrict__ gdiff, float* __restrict__ out) {
    int s = 0;
    for (int i = threadIdx.x; i < PLANES * BINS; i += TPB) {
        int v = gdiff[i];
        s += (v < 0) ? -v : v;
    }
    // wave64 butterfly
#pragma unroll
    for (int off = 32; off > 0; off >>= 1) s += __shfl_down(s, off, 64);
    __shared__ int ws[TPB / 64];
    const int wid  = threadIdx.x >> 6;
    const int lane = threadIdx.x & 63;
    if (lane == 0) ws[wid] = s;
    __syncthreads();
    if (threadIdx.x == 0) {
        int total = 0;
#pragma unroll
        for (int w = 0; w < TPB / 64; ++w) total += ws[w];
        // loss = total / N / (B*C*BINS); total < 2^24 so exact in fp32
        out[0] = (float)total * (1.0f / (262144.0f * 6144.0f));
    }
}

extern "C" void kernel_launch(void* const* d_in, const int* in_sizes, int n_in,
                              void* d_out, int out_size, void* d_ws, size_t ws_size,
                              hipStream_t stream) {
    const float4* inp = (const float4*)d_in[0];
    const float4* tgt = (const float4*)d_in[1];
    int* gdiff = (int*)d_ws;   // 96*64 signed counts, 24 KiB

    hipMemsetAsync(gdiff, 0, PLANES * BINS * sizeof(int), stream);
    hist_diff_kernel<<<PLANES * SEGS, TPB, 0, stream>>>(inp, tgt, gdiff);
    reduce_abs_kernel<<<1, TPB, 0, stream>>>(gdiff, (float*)d_out);
}

// Round 4
// 214.816 us; speedup vs baseline: 1.2053x; 1.2053x over previous
//
#include <hip/hip_runtime.h>

// ColorHistogramLoss: B=32, C=3, H=W=512, BINS=64.
// v3c: per-thread PRIVATE u16 histogram columns in LDS — no atomics, no ballots
// in the hot loop. hist[row][tid] with 512B row stride -> bank = tid>>1
// (exactly 2 lanes/bank = free, independent of data-dependent bin).
// Per element: ds_read_u16 + add + ds_write_b16 on a thread-owned column.
// Merge: ds_read_b128 + packed s16 adds, diagonal bank-balanced.
// v3b->v3c: __align__(16) on the LDS array (b128 access of a short array was
// only 2B-aligned by contract — potential fault); removed launch_bounds hint.

#define BINS 64
#define PLANES 96          // B*C
#define PLANE_F4 65536     // 512*512/4
#define SEGS 32            // segments per plane
#define SEG_F4 2048        // PLANE_F4/SEGS
#define TPB 256
#define F4T 8              // float4 per thread per tensor
#define NROWS 65           // 64 bins + trash row for v < -1
#define LDS_U32 (NROWS * 256 * 2 / 4)   // 8320 words = 33280 B

typedef short short2v __attribute__((ext_vector_type(2)));

// bin = trunc((v+1)*31.5) (== floor since arg >= 0 for v >= -1); v>=1 -> 63; v<-1 -> trash.
// EXACT same arithmetic as the absmax==0-verified v1 formula.
__device__ __forceinline__ void bump(unsigned short* __restrict__ col, float v, int delta) {
    int bin = (int)((v + 1.0f) * 31.5f);
    bin = bin > 63 ? 63 : bin;
    int row = (v < -1.0f) ? 64 : bin;
    col[row * 256] = (unsigned short)(col[row * 256] + delta);  // u16 wrap == mod-65536 signed
}

__global__ __launch_bounds__(TPB) void hist_diff_kernel(
        const float4* __restrict__ in4, const float4* __restrict__ tg4,
        int* __restrict__ gdiff) {
    __shared__ __align__(16) unsigned short hist[NROWS][256];   // 33280 B -> 4 blocks/CU

    const int tid  = threadIdx.x;
    const int lane = tid & 63;
    const int wid  = tid >> 6;

    // zero LDS with b128 stores
    {
        uint4* p = (uint4*)&hist[0][0];
#pragma unroll
        for (int i = 0; i < 9; ++i) {
            int idx = tid + i * TPB;
            if (idx < LDS_U32 / 4) p[idx] = make_uint4(0, 0, 0, 0);
        }
    }
    __syncthreads();

    const int plane = blockIdx.x >> 5;           // /SEGS
    const int seg   = blockIdx.x & (SEGS - 1);
    const long base = (long)plane * PLANE_F4 + (long)seg * SEG_F4 + tid;

    // stage all 16 float4 loads up front; vmcnt pipelining hides HBM/L3 latency
    float4 a[F4T], b[F4T];
#pragma unroll
    for (int k = 0; k < F4T; ++k) a[k] = in4[base + k * TPB];
#pragma unroll
    for (int k = 0; k < F4T; ++k) b[k] = tg4[base + k * TPB];

    unsigned short* col = &hist[0][tid];
#pragma unroll
    for (int k = 0; k < F4T; ++k) {
        bump(col, a[k].x, 1); bump(col, a[k].y, 1);
        bump(col, a[k].z, 1); bump(col, a[k].w, 1);
    }
#pragma unroll
    for (int k = 0; k < F4T; ++k) {
        bump(col, b[k].x, -1); bump(col, b[k].y, -1);
        bump(col, b[k].z, -1); bump(col, b[k].w, -1);
    }
    __syncthreads();

    // merge: wave w sums columns [w*64, w*64+64) of row 'lane' (bin), 8x ds_read_b128.
    // diagonal j=(it+lane)&7 spreads the 8 reads across all 32 banks (balanced).
    {
        const uint4* rowp = (const uint4*)&hist[lane][wid * 64];
        short2v acc; acc.x = 0; acc.y = 0;
#pragma unroll
        for (int it = 0; it < 8; ++it) {
            int j = (it + lane) & 7;
            uint4 w4 = rowp[j];
            union { uint4 u; short2v s2[4]; } cv; cv.u = w4;
            acc = acc + cv.s2[0];
            acc = acc + cv.s2[1];
            acc = acc + cv.s2[2];
            acc = acc + cv.s2[3];
        }
        // per-parity partials: 32 columns x |count|<=32 -> |acc| <= 1024, exact in s16
        int s = (int)acc.x + (int)acc.y;
        if (s != 0) atomicAdd(&gdiff[plane * BINS + lane], s);  // 64 distinct addrs/wave
    }
}

__global__ __launch_bounds__(TPB) void reduce_abs_kernel(
        const int* __restrict__ gdiff, float* __restrict__ out) {
    int s = 0;
    for (int i = threadIdx.x; i < PLANES * BINS; i += TPB) {
        int v = gdiff[i];
        s += (v < 0) ? -v : v;
    }
    // wave64 butterfly
#pragma unroll
    for (int off = 32; off > 0; off >>= 1) s += __shfl_down(s, off, 64);
    __shared__ int ws[TPB / 64];
    const int wid  = threadIdx.x >> 6;
    const int lane = threadIdx.x & 63;
    if (lane == 0) ws[wid] = s;
    __syncthreads();
    if (threadIdx.x == 0) {
        int total = 0;
#pragma unroll
        for (int w = 0; w < TPB / 64; ++w) total += ws[w];
        // loss = total / N / (B*C*BINS); |total| < 2^24 so exact in fp32
        out[0] = (float)total * (1.0f / (262144.0f * 6144.0f));
    }
}

extern "C" void kernel_launch(void* const* d_in, const int* in_sizes, int n_in,
                              void* d_out, int out_size, void* d_ws, size_t ws_size,
                              hipStream_t stream) {
    const float4* inp = (const float4*)d_in[0];
    const float4* tgt = (const float4*)d_in[1];
    int* gdiff = (int*)d_ws;   // 96*64 signed counts, 24 KiB

    hipMemsetAsync(gdiff, 0, PLANES * BINS * sizeof(int), stream);
    hist_diff_kernel<<<PLANES * SEGS, TPB, 0, stream>>>(inp, tgt, gdiff);
    reduce_abs_kernel<<<1, TPB, 0, stream>>>(gdiff, (float*)d_out);
}